// Round 25
// baseline (124.698 us; speedup 1.0000x reference)
//
#include <hip/hip_runtime.h>
#include <stdint.h>

typedef unsigned short u16t;
typedef __attribute__((ext_vector_type(8))) short bf16x8;
typedef __attribute__((ext_vector_type(4))) float f32x4;

#define DEV __device__ __forceinline__

DEV u16t f2bf(float f) {
  union { float f; unsigned u; } v; v.f = f;
  unsigned r = v.u + 0x7FFFu + ((v.u >> 16) & 1u);
  return (u16t)(r >> 16);
}

// packed f32x2 -> bf16x2 (lo <- a, hi <- b), single VALU op
DEV unsigned cvtpk(float a, float b) {
  unsigned r;
  asm("v_cvt_pk_bf16_f32 %0, %1, %2" : "=v"(r) : "v"(a), "v"(b));
  return r;
}

DEV void glds16(const void* g, void* l) {
  __builtin_amdgcn_global_load_lds((const __attribute__((address_space(1))) void*)g,
                                   (__attribute__((address_space(3))) void*)l, 16, 0, 0);
}

// ---------------- fused prep: cast x + transpose-cast both weights ----------
DEV void transpose_tile(const float* __restrict__ src, u16t* __restrict__ dst,
                        int R, int C, int c0, int r0, u16t (*tile)[65]) {
  int tid = threadIdx.x;
#pragma unroll
  for (int i = 0; i < 16; i++) {
    int idx = tid + i * 256;
    int r = idx >> 6, c = idx & 63;
    tile[c][r] = f2bf(src[(size_t)(r0 + r) * C + (c0 + c)]);
  }
  __syncthreads();
#pragma unroll
  for (int i = 0; i < 16; i++) {
    int idx = tid + i * 256;
    int rr = idx >> 6, cc = idx & 63;
    dst[(size_t)(c0 + rr) * R + (r0 + cc)] = tile[rr][cc];
  }
}

__global__ __launch_bounds__(256) void k_prep(const float* __restrict__ x,
                                              u16t* __restrict__ xb,
                                              const float* __restrict__ Wqkv,
                                              u16t* __restrict__ wqkvT,
                                              const float* __restrict__ Wout,
                                              u16t* __restrict__ woutT) {
  __shared__ u16t tile[64][65];
  const int bid = blockIdx.x;
  if (bid < 2048) {
    int i = (bid * 256 + threadIdx.x) * 8;
    const float4* p = (const float4*)(x + i);
    float4 a = p[0], b = p[1];
    union { u16t h[8]; int4 v; } o;
    o.h[0] = f2bf(a.x); o.h[1] = f2bf(a.y); o.h[2] = f2bf(a.z); o.h[3] = f2bf(a.w);
    o.h[4] = f2bf(b.x); o.h[5] = f2bf(b.y); o.h[6] = f2bf(b.z); o.h[7] = f2bf(b.w);
    *(int4*)(xb + i) = o.v;
  } else if (bid < 2816) {
    int b2 = bid - 2048;
    transpose_tile(Wqkv, wqkvT, 1024, 3072, (b2 % 48) * 64, (b2 / 48) * 64, tile);
  } else {
    int b3 = bid - 2816;
    transpose_tile(Wout, woutT, 1024, 1024, (b3 & 15) * 64, (b3 >> 4) * 64, tile);
  }
}

// ------------- templated GEMM mainloop: C = A[M,K] * Bt[N,K]^T -------------
template <int K, int BM, int BN>
DEV void gemm_mainloop_t(const u16t* __restrict__ A, const u16t* __restrict__ Bt,
                         int m0, int n0, u16t* ldsA, u16t* ldsB,
                         f32x4 (&acc)[BM / 32][BN / 32]) {
  constexpr int MF = BM / 32, NF = BN / 32;
  const int tid = threadIdx.x;
  const int lane = tid & 63;
  const int wid = tid >> 6;
  const int wm = wid >> 1, wn = wid & 1;
#pragma unroll
  for (int i = 0; i < MF; i++)
#pragma unroll
    for (int j = 0; j < NF; j++) acc[i][j] = f32x4{0.f, 0.f, 0.f, 0.f};

  char* lA = (char*)ldsA;
  char* lB = (char*)ldsB;

  for (int k0 = 0; k0 < K; k0 += 32) {
#pragma unroll
    for (int j = wid; j < BM / 16; j += 4) {
      int g = j * 64 + lane;
      int row = g >> 2;
      int cb = (g & 3) * 16;
      glds16((const char*)(A + (size_t)(m0 + row) * K + k0) + cb, lA + j * 1024);
    }
#pragma unroll
    for (int j = wid; j < BN / 16; j += 4) {
      int g = j * 64 + lane;
      int row = g >> 2;
      int cb = (g & 3) * 16;
      glds16((const char*)(Bt + (size_t)(n0 + row) * K + k0) + cb, lB + j * 1024);
    }
    __syncthreads();
    bf16x8 af[MF], bfr[NF];
    const int lr = lane & 15;
    const int ko = (lane >> 4) * 8;
#pragma unroll
    for (int f = 0; f < MF; f++)
      af[f] = *(const bf16x8*)(ldsA + (wm * (BM / 2) + f * 16 + lr) * 32 + ko);
#pragma unroll
    for (int f = 0; f < NF; f++)
      bfr[f] = *(const bf16x8*)(ldsB + (wn * (BN / 2) + f * 16 + lr) * 32 + ko);
#pragma unroll
    for (int i = 0; i < MF; i++)
#pragma unroll
      for (int j = 0; j < NF; j++)
        acc[i][j] = __builtin_amdgcn_mfma_f32_16x16x32_bf16(af[i], bfr[j], acc[i][j], 0, 0, 0);
    __syncthreads();
  }
}

// ---------------- GEMM1: qkv = xb @ WqkvT^T + b, scatter to q/k/vt ----------------
__global__ __launch_bounds__(256) void k_gemm_qkv(const u16t* __restrict__ xb,
                                                  const u16t* __restrict__ wt,
                                                  const float* __restrict__ bias,
                                                  u16t* __restrict__ q,
                                                  u16t* __restrict__ kk,
                                                  u16t* __restrict__ vt) {
  __shared__ alignas(16) char pool[32768];
  u16t* ldsA = (u16t*)pool;
  u16t* ldsB = (u16t*)(pool + 8192);
  const int m0 = blockIdx.x * 128, n0 = blockIdx.y * 128;
  f32x4 acc[4][4];
  gemm_mainloop_t<1024, 128, 128>(xb, wt, m0, n0, ldsA, ldsB, acc);

  const int lane = threadIdx.x & 63, wid = threadIdx.x >> 6;
  const int wm = wid >> 1, wn = wid & 1;
  const int nbase = n0 + wn * 64;
  const int which = nbase >> 10;
  const int hb = (nbase & 1023) >> 6;
  const int bb = m0 >> 11;
  const int t0 = (m0 & 2047) + wm * 64;
  const int bh = bb * 16 + hb;
  u16t* eb = (u16t*)(pool + wid * 8192);
#pragma unroll
  for (int fm = 0; fm < 4; fm++) {
#pragma unroll
    for (int fn = 0; fn < 4; fn++) {
      float bv = bias[nbase + fn * 16 + (lane & 15)];
#pragma unroll
      for (int i = 0; i < 4; i++) {
        int t_loc = fm * 16 + (lane >> 4) * 4 + i;
        int d_loc = fn * 16 + (lane & 15);
        float v = acc[fm][fn][i] + bv;
        if (which == 2) eb[d_loc * 64 + t_loc] = f2bf(v);
        else            eb[t_loc * 64 + d_loc] = f2bf(v);
      }
    }
  }
  asm volatile("s_waitcnt lgkmcnt(0)" ::: "memory");
  u16t* dst;
  size_t base, rowstride;
  if (which == 2) { dst = vt; base = (size_t)bh * 64 * 2048 + t0; rowstride = 2048; }
  else { dst = (which == 0) ? q : kk; base = ((size_t)bh * 2048 + t0) * 64; rowstride = 64; }
#pragma unroll
  for (int it = 0; it < 8; it++) {
    int g = it * 64 + lane;
    int r = g >> 3;
    int ce = (g & 7) * 8;
    *(int4*)(dst + base + (size_t)r * rowstride + ce) = *(const int4*)(eb + r * 64 + ce);
  }
}

// ---------------- flash attention, causal, BARRIER-FREE 1-wave blocks --------
// 64-thr blocks (1 wave, 16 q-rows), paired 16-row q-tiles t_lo=p / t_hi=127-p
// -> 2048 uniform blocks, XCD-chunked. Wave-PRIVATE K/V/P staging (18 KB LDS)
// -> 8 independent blocks/CU = 2 independent waves/SIMD that cover each
// other's stalls. ZERO __syncthreads: wave-coherent LDS, only s_waitcnt
// vmcnt(0) after stage. Compute core identical to R24 (fixed-max softmax,
// swapped MFMA, cvt_pk, XOR swizzles).
__global__ __launch_bounds__(64) void k_attn(const u16t* __restrict__ q,
                                             const u16t* __restrict__ kk,
                                             const u16t* __restrict__ vt,
                                             u16t* __restrict__ attn) {
  __shared__ u16t ldsK[64 * 64];      // [kv][d] 128B rows, swizzled (8 KB)
  __shared__ u16t ldsV[64 * 64];      // [d][kv] 128B rows, swizzled (8 KB)
  __shared__ u16t ldsP[16 * 64];      // P[q][kv], swizzled (2 KB)
  const int lin = blockIdx.x;                   // 0..2047
  const int swz = (lin & 7) * 256 + (lin >> 3); // XCD chunk = 256 = 4 bh groups
  const int bh = swz >> 6;
  const int pr = swz & 63;
  const int t_lo = pr, t_hi = 127 - pr;         // 16-row q-tiles
  const int lo_last = t_lo >> 2, hi_last = t_hi >> 2;   // last 64-kv tile idx
  const int lane = threadIdx.x;
  const int lr = lane & 15, lg = lane >> 4;
  const size_t hbase = (size_t)bh * 2048 * 64;
  const size_t vbase = (size_t)bh * 64 * 2048;
  const float NINF = -__builtin_inff();
  const float CEXP = 0.1803368801111204f;   // log2(e) / sqrt(64)
  const float NMC  = -48.0f * 0.1803368801111204f;  // fixed softmax offset

  bf16x8 qlo[2], qhi[2];
  {
    const u16t* qp  = q + hbase + (size_t)(t_lo * 16 + lr) * 64 + lg * 8;
    const u16t* qp2 = q + hbase + (size_t)(t_hi * 16 + lr) * 64 + lg * 8;
#pragma unroll
    for (int ks = 0; ks < 2; ks++) {
      qlo[ks] = *(const bf16x8*)(qp + ks * 32);
      qhi[ks] = *(const bf16x8*)(qp2 + ks * 32);
    }
  }

  f32x4 olo[4], ohi[4];
#pragma unroll
  for (int i = 0; i < 4; i++) {
    olo[i] = f32x4{0.f, 0.f, 0.f, 0.f};
    ohi[i] = f32x4{0.f, 0.f, 0.f, 0.f};
  }
  float llo = 0.f, lhi = 0.f;   // lane-partial softmax denominators

  // stage one 64x64 K tile + 64x64 V^T tile; 8+8 glds16 per lane
  auto stage = [&](int kt) {
#pragma unroll
    for (int j = 0; j < 8; j++) {
      int g = j * 64 + lane;
      int r = g >> 3;             // 8 granules per 128B row
      int cb = (g & 7) * 16;
      int sc = cb ^ ((r & 7) << 4);
      glds16((const char*)(kk + hbase + (size_t)(kt * 64 + r) * 64) + sc,
             (char*)ldsK + j * 1024);
      glds16((const char*)(vt + vbase + (size_t)r * 2048 + kt * 64) + sc,
             (char*)ldsV + j * 1024);
    }
  };

  auto compute = [&](bool diag, int moff, const bf16x8* qf, f32x4* o, float& l_part) {
    const char* K = (const char*)ldsK;
    const char* V = (const char*)ldsV;
    float sv[4][4];   // sv[f][i] = S^T[kv = 16f + 4lg + i][q = lr]
    __builtin_amdgcn_s_setprio(1);
#pragma unroll
    for (int f = 0; f < 4; f++) {
      f32x4 s = f32x4{0.f, 0.f, 0.f, 0.f};
#pragma unroll
      for (int ks = 0; ks < 2; ks++) {
        int row = f * 16 + lr;
        int cb = ks * 64 + lg * 16;
        bf16x8 kf = *(const bf16x8*)(K + row * 128 + (cb ^ ((row & 7) << 4)));
        s = __builtin_amdgcn_mfma_f32_16x16x32_bf16(kf, qf[ks], s, 0, 0, 0);
      }
#pragma unroll
      for (int i = 0; i < 4; i++) sv[f][i] = s[i];
    }
    __builtin_amdgcn_s_setprio(0);
    if (diag) {
      int qr = moff + lr;
#pragma unroll
      for (int f = 0; f < 4; f++)
#pragma unroll
        for (int i = 0; i < 4; i++)
          if (f * 16 + lg * 4 + i > qr) sv[f][i] = NINF;
    }
    // fixed-max softmax: p = 2^(s*CEXP + NMC); fully lane-local
    float ps[4][4];
    float fs[4];
#pragma unroll
    for (int f = 0; f < 4; f++) {
#pragma unroll
      for (int i = 0; i < 4; i++)
        ps[f][i] = exp2f(__builtin_fmaf(sv[f][i], CEXP, NMC));
      fs[f] = (ps[f][0] + ps[f][1]) + (ps[f][2] + ps[f][3]);
    }
    l_part += (fs[0] + fs[1]) + (fs[2] + fs[3]);
    // P[q=lr][kv]: pack 4 consecutive kv via 2 cvt_pk -> one 8B swizzled write
#pragma unroll
    for (int f = 0; f < 4; f++) {
      union { unsigned u[2]; uint2 v; } pk;
      pk.u[0] = cvtpk(ps[f][0], ps[f][1]);
      pk.u[1] = cvtpk(ps[f][2], ps[f][3]);
      int cby = (f * 32 + lg * 8) ^ ((lr & 7) << 4);
      *(uint2*)((char*)ldsP + lr * 128 + cby) = pk.v;
    }
    asm volatile("s_waitcnt lgkmcnt(0)" ::: "memory");
    __builtin_amdgcn_s_setprio(1);
#pragma unroll
    for (int ks = 0; ks < 2; ks++) {
      int cb = ks * 64 + lg * 16;
      bf16x8 pf = *(const bf16x8*)((const char*)ldsP + lr * 128 + (cb ^ ((lr & 7) << 4)));
#pragma unroll
      for (int df = 0; df < 4; df++) {
        int vrow = df * 16 + lr;
        bf16x8 vf = *(const bf16x8*)(V + vrow * 128 + (cb ^ ((vrow & 7) << 4)));
        o[df] = __builtin_amdgcn_mfma_f32_16x16x32_bf16(vf, pf, o[df], 0, 0, 0);
      }
    }
    __builtin_amdgcn_s_setprio(0);
  };

  for (int kt = 0; kt <= hi_last; kt++) {
    stage(kt);
    asm volatile("s_waitcnt vmcnt(0)" ::: "memory");   // wave-private staging
    compute(kt == hi_last, (t_hi & 3) << 4, qhi, ohi, lhi);
    if (kt <= lo_last) compute(kt == lo_last, (t_lo & 3) << 4, qlo, olo, llo);
  }

  const int bb = bh >> 4, h = bh & 15;
  auto epi = [&](int qt, const f32x4* o, float l_part) {
    float l = l_part;
    l += __shfl_xor(l, 16);
    l += __shfl_xor(l, 32);
    float rinv = 1.0f / l;
    int t = qt * 16 + lr;
    size_t rowb = ((size_t)bb * 2048 + t) * 1024 + h * 64;
#pragma unroll
    for (int df = 0; df < 4; df++) {
      union { unsigned u[2]; uint2 v; } pk;
      pk.u[0] = cvtpk(o[df][0] * rinv, o[df][1] * rinv);
      pk.u[1] = cvtpk(o[df][2] * rinv, o[df][3] * rinv);
      *(uint2*)(attn + rowb + df * 16 + lg * 4) = pk.v;
    }
  };
  epi(t_lo, olo, llo);
  epi(t_hi, ohi, lhi);
}

// ---------------- GEMM2: out = attn @ WoutT^T + b_out (fp32 out) ----------------
__global__ __launch_bounds__(256) void k_gemm_out(const u16t* __restrict__ attn,
                                                  const u16t* __restrict__ wt,
                                                  const float* __restrict__ bias,
                                                  float* __restrict__ out) {
  __shared__ u16t ldsA[64 * 32];
  __shared__ u16t ldsB[128 * 32];
  const int m0 = blockIdx.x * 64, n0 = blockIdx.y * 128;
  f32x4 acc[2][4];
  gemm_mainloop_t<1024, 64, 128>(attn, wt, m0, n0, ldsA, ldsB, acc);

  const int lane = threadIdx.x & 63, wid = threadIdx.x >> 6;
  const int wm = wid >> 1, wn = wid & 1;
#pragma unroll
  for (int fm = 0; fm < 2; fm++) {
    int row = m0 + wm * 32 + fm * 16 + (lane >> 4) * 4;
#pragma unroll
    for (int fn = 0; fn < 4; fn++) {
      int col = n0 + wn * 64 + fn * 16 + (lane & 15);
      float bv = bias[col];
#pragma unroll
      for (int i = 0; i < 4; i++)
        out[(size_t)(row + i) * 1024 + col] = acc[fm][fn][i] + bv;
    }
  }
}

extern "C" void kernel_launch(void* const* d_in, const int* in_sizes, int n_in,
                              void* d_out, int out_size, void* d_ws, size_t ws_size,
                              hipStream_t stream) {
  const float* x     = (const float*)d_in[0];
  const float* W_qkv = (const float*)d_in[1];
  const float* b_qkv = (const float*)d_in[2];
  const float* W_out = (const float*)d_in[3];
  const float* b_out = (const float*)d_in[4];
  float* out = (float*)d_out;

  char* ws = (char*)d_ws;
  u16t* xb    = (u16t*)(ws);
  u16t* wqkvT = (u16t*)(ws + 8388608);
  u16t* woutT = (u16t*)(ws + 14680064);
  u16t* qb    = (u16t*)(ws + 16777216);
  u16t* kb    = (u16t*)(ws + 25165824);
  u16t* vtb   = (u16t*)(ws + 33554432);
  u16t* attnb = (u16t*)(ws + 41943040);

  k_prep<<<3072, 256, 0, stream>>>(x, xb, W_qkv, wqkvT, W_out, woutT);
  k_gemm_qkv<<<dim3(32, 24), 256, 0, stream>>>(xb, wqkvT, b_qkv, qb, kb, vtb);
  k_attn<<<2048, 64, 0, stream>>>(qb, kb, vtb, attnb);
  k_gemm_out<<<dim3(64, 8), 256, 0, stream>>>(attnb, woutT, b_out, out);
}

// Round 26
// 117.812 us; speedup vs baseline: 1.0585x; 1.0585x over previous
//
#include <hip/hip_runtime.h>
#include <stdint.h>

typedef unsigned short u16t;
typedef __attribute__((ext_vector_type(8))) short bf16x8;
typedef __attribute__((ext_vector_type(4))) float f32x4;

#define DEV __device__ __forceinline__

DEV u16t f2bf(float f) {
  union { float f; unsigned u; } v; v.f = f;
  unsigned r = v.u + 0x7FFFu + ((v.u >> 16) & 1u);
  return (u16t)(r >> 16);
}

// packed f32x2 -> bf16x2 (lo <- a, hi <- b), single VALU op
DEV unsigned cvtpk(float a, float b) {
  unsigned r;
  asm("v_cvt_pk_bf16_f32 %0, %1, %2" : "=v"(r) : "v"(a), "v"(b));
  return r;
}

DEV void glds16(const void* g, void* l) {
  __builtin_amdgcn_global_load_lds((const __attribute__((address_space(1))) void*)g,
                                   (__attribute__((address_space(3))) void*)l, 16, 0, 0);
}

// ---------------- fused prep: cast x + transpose-cast both weights ----------
// blocks [0,2048): cast x f32->bf16 (8 elems/thread)
// blocks [2048,2816): transpose W_qkv 1024x3072 -> wqkvT
// blocks [2816,3072): transpose W_out 1024x1024 -> woutT
DEV void transpose_tile(const float* __restrict__ src, u16t* __restrict__ dst,
                        int R, int C, int c0, int r0, u16t (*tile)[65]) {
  int tid = threadIdx.x;
#pragma unroll
  for (int i = 0; i < 16; i++) {
    int idx = tid + i * 256;
    int r = idx >> 6, c = idx & 63;
    tile[c][r] = f2bf(src[(size_t)(r0 + r) * C + (c0 + c)]);
  }
  __syncthreads();
#pragma unroll
  for (int i = 0; i < 16; i++) {
    int idx = tid + i * 256;
    int rr = idx >> 6, cc = idx & 63;
    dst[(size_t)(c0 + rr) * R + (r0 + cc)] = tile[rr][cc];
  }
}

__global__ __launch_bounds__(256) void k_prep(const float* __restrict__ x,
                                              u16t* __restrict__ xb,
                                              const float* __restrict__ Wqkv,
                                              u16t* __restrict__ wqkvT,
                                              const float* __restrict__ Wout,
                                              u16t* __restrict__ woutT) {
  __shared__ u16t tile[64][65];
  const int bid = blockIdx.x;
  if (bid < 2048) {
    int i = (bid * 256 + threadIdx.x) * 8;
    const float4* p = (const float4*)(x + i);
    float4 a = p[0], b = p[1];
    union { u16t h[8]; int4 v; } o;
    o.h[0] = f2bf(a.x); o.h[1] = f2bf(a.y); o.h[2] = f2bf(a.z); o.h[3] = f2bf(a.w);
    o.h[4] = f2bf(b.x); o.h[5] = f2bf(b.y); o.h[6] = f2bf(b.z); o.h[7] = f2bf(b.w);
    *(int4*)(xb + i) = o.v;
  } else if (bid < 2816) {
    int b2 = bid - 2048;
    transpose_tile(Wqkv, wqkvT, 1024, 3072, (b2 % 48) * 64, (b2 / 48) * 64, tile);
  } else {
    int b3 = bid - 2816;
    transpose_tile(Wout, woutT, 1024, 1024, (b3 & 15) * 64, (b3 >> 4) * 64, tile);
  }
}

// ------------- templated GEMM mainloop: C = A[M,K] * Bt[N,K]^T -------------
// 256 thr = 4 waves (2x2); block tile BM x BN; wave tile BM/2 x BN/2; BK=32.
template <int K, int BM, int BN>
DEV void gemm_mainloop_t(const u16t* __restrict__ A, const u16t* __restrict__ Bt,
                         int m0, int n0, u16t* ldsA, u16t* ldsB,
                         f32x4 (&acc)[BM / 32][BN / 32]) {
  constexpr int MF = BM / 32, NF = BN / 32;
  const int tid = threadIdx.x;
  const int lane = tid & 63;
  const int wid = tid >> 6;
  const int wm = wid >> 1, wn = wid & 1;
#pragma unroll
  for (int i = 0; i < MF; i++)
#pragma unroll
    for (int j = 0; j < NF; j++) acc[i][j] = f32x4{0.f, 0.f, 0.f, 0.f};

  char* lA = (char*)ldsA;
  char* lB = (char*)ldsB;

  for (int k0 = 0; k0 < K; k0 += 32) {
#pragma unroll
    for (int j = wid; j < BM / 16; j += 4) {
      int g = j * 64 + lane;
      int row = g >> 2;          // 4 granules per 64B row
      int cb = (g & 3) * 16;
      glds16((const char*)(A + (size_t)(m0 + row) * K + k0) + cb, lA + j * 1024);
    }
#pragma unroll
    for (int j = wid; j < BN / 16; j += 4) {
      int g = j * 64 + lane;
      int row = g >> 2;
      int cb = (g & 3) * 16;
      glds16((const char*)(Bt + (size_t)(n0 + row) * K + k0) + cb, lB + j * 1024);
    }
    __syncthreads();
    bf16x8 af[MF], bfr[NF];
    const int lr = lane & 15;
    const int ko = (lane >> 4) * 8;
#pragma unroll
    for (int f = 0; f < MF; f++)
      af[f] = *(const bf16x8*)(ldsA + (wm * (BM / 2) + f * 16 + lr) * 32 + ko);
#pragma unroll
    for (int f = 0; f < NF; f++)
      bfr[f] = *(const bf16x8*)(ldsB + (wn * (BN / 2) + f * 16 + lr) * 32 + ko);
#pragma unroll
    for (int i = 0; i < MF; i++)
#pragma unroll
      for (int j = 0; j < NF; j++)
        acc[i][j] = __builtin_amdgcn_mfma_f32_16x16x32_bf16(af[i], bfr[j], acc[i][j], 0, 0, 0);
    __syncthreads();
  }
}

// ---------------- GEMM1: qkv = xb @ WqkvT^T + b, scatter to q/k/vt ----------------
// LDS: 32 KB pool — A(8K)+B(8K) live during mainloop; the 32 KB epilogue
// staging overlaps them (A/B dead after the mainloop's final barrier).
__global__ __launch_bounds__(256) void k_gemm_qkv(const u16t* __restrict__ xb,
                                                  const u16t* __restrict__ wt,
                                                  const float* __restrict__ bias,
                                                  u16t* __restrict__ q,
                                                  u16t* __restrict__ kk,
                                                  u16t* __restrict__ vt) {
  __shared__ alignas(16) char pool[32768];
  u16t* ldsA = (u16t*)pool;
  u16t* ldsB = (u16t*)(pool + 8192);
  const int m0 = blockIdx.x * 128, n0 = blockIdx.y * 128;
  f32x4 acc[4][4];
  gemm_mainloop_t<1024, 128, 128>(xb, wt, m0, n0, ldsA, ldsB, acc);
  // mainloop ends with __syncthreads(): all waves done reading A/B -> pool reusable

  const int lane = threadIdx.x & 63, wid = threadIdx.x >> 6;
  const int wm = wid >> 1, wn = wid & 1;
  const int nbase = n0 + wn * 64;
  const int which = nbase >> 10;
  const int hb = (nbase & 1023) >> 6;
  const int bb = m0 >> 11;
  const int t0 = (m0 & 2047) + wm * 64;
  const int bh = bb * 16 + hb;
  u16t* eb = (u16t*)(pool + wid * 8192);   // per-wave 64x64 staging, disjoint
#pragma unroll
  for (int fm = 0; fm < 4; fm++) {
#pragma unroll
    for (int fn = 0; fn < 4; fn++) {
      float bv = bias[nbase + fn * 16 + (lane & 15)];
#pragma unroll
      for (int i = 0; i < 4; i++) {
        int t_loc = fm * 16 + (lane >> 4) * 4 + i;
        int d_loc = fn * 16 + (lane & 15);
        float v = acc[fm][fn][i] + bv;
        if (which == 2) eb[d_loc * 64 + t_loc] = f2bf(v);
        else            eb[t_loc * 64 + d_loc] = f2bf(v);
      }
    }
  }
  asm volatile("s_waitcnt lgkmcnt(0)" ::: "memory");  // wave-internal LDS bounce
  u16t* dst;
  size_t base, rowstride;
  if (which == 2) { dst = vt; base = (size_t)bh * 64 * 2048 + t0; rowstride = 2048; }
  else { dst = (which == 0) ? q : kk; base = ((size_t)bh * 2048 + t0) * 64; rowstride = 64; }
#pragma unroll
  for (int it = 0; it < 8; it++) {
    int g = it * 64 + lane;
    int r = g >> 3;
    int ce = (g & 7) * 8;
    *(int4*)(dst + base + (size_t)r * rowstride + ce) = *(const int4*)(eb + r * 64 + ce);
  }
}

// ---------------- flash attention, causal, paired q-tiles, KVBLK=128 ----------
// (R12 exact: XCD-chunked swizzle + fixed-max softmax, single-buffered)
__global__ __launch_bounds__(128) void k_attn(const u16t* __restrict__ q,
                                              const u16t* __restrict__ kk,
                                              const u16t* __restrict__ vt,
                                              u16t* __restrict__ attn) {
  __shared__ u16t ldsK[128 * 64];     // [kv][d]  128B rows, swizzled
  __shared__ u16t ldsV[64 * 128];     // [d][kv]  256B rows, swizzled
  __shared__ u16t ldsP[2][16 * 128];  // per-wave P[q][kv] 256B rows, swizzled
  const int lin = blockIdx.x;                   // 0..1023
  const int swz = (lin & 7) * 128 + (lin >> 3); // XCD-chunked
  const int p = swz & 31;
  const int bh = swz >> 5;
  const int t_lo = p, t_hi = 63 - p;            // 32-row q-tiles
  const int lo_last = t_lo >> 2, hi_last = t_hi >> 2;   // last 128-kv tile idx
  const int tid = threadIdx.x;
  const int lane = tid & 63, wid = tid >> 6;
  const int lr = lane & 15, lg = lane >> 4;
  const size_t hbase = (size_t)bh * 2048 * 64;
  const size_t vbase = (size_t)bh * 64 * 2048;
  const float NINF = -__builtin_inff();
  const float CEXP = 0.1803368801111204f;   // log2(e) / sqrt(64)
  const float NMC  = -48.0f * 0.1803368801111204f;  // fixed softmax offset

  bf16x8 qlo[2], qhi[2];
  {
    const u16t* qp  = q + hbase + (size_t)(t_lo * 32 + wid * 16 + lr) * 64 + lg * 8;
    const u16t* qp2 = q + hbase + (size_t)(t_hi * 32 + wid * 16 + lr) * 64 + lg * 8;
#pragma unroll
    for (int ks = 0; ks < 2; ks++) {
      qlo[ks] = *(const bf16x8*)(qp + ks * 32);
      qhi[ks] = *(const bf16x8*)(qp2 + ks * 32);
    }
  }

  f32x4 olo[4], ohi[4];
#pragma unroll
  for (int i = 0; i < 4; i++) {
    olo[i] = f32x4{0.f, 0.f, 0.f, 0.f};
    ohi[i] = f32x4{0.f, 0.f, 0.f, 0.f};
  }
  float llo = 0.f, lhi = 0.f;   // lane-partial softmax denominators

  u16t* pb = ldsP[wid];

  // stage 128x64 K tile (16KB) + 64x128 V^T tile (16KB); 8+8 granules/thread
  auto stage = [&](int kt) {
#pragma unroll
    for (int j = 0; j < 8; j++) {
      int g = j * 128 + tid;
      {  // K: row = kv (128B rows)
        int r = g >> 3;
        int cb = (g & 7) * 16;
        int sc = cb ^ ((r & 7) << 4);
        glds16((const char*)(kk + hbase + (size_t)(kt * 128 + r) * 64) + sc,
               (char*)ldsK + j * 2048 + wid * 1024);
      }
      {  // V^T: row = d (256B rows)
        int r = g >> 4;
        int cb = (g & 15) * 16;
        int sc = cb ^ ((r & 7) << 4);
        glds16((const char*)(vt + vbase + (size_t)r * 2048 + kt * 128) + sc,
               (char*)ldsV + j * 2048 + wid * 1024);
      }
    }
  };

  auto compute = [&](bool diag, int moff, const bf16x8* qf, f32x4* o, float& l_part) {
    const char* K = (const char*)ldsK;
    const char* V = (const char*)ldsV;
    float sv[8][4];   // sv[f][i] = S^T[kv = 16f + 4lg + i][q = lr]
    __builtin_amdgcn_s_setprio(1);
#pragma unroll
    for (int f = 0; f < 8; f++) {
      f32x4 s = f32x4{0.f, 0.f, 0.f, 0.f};
#pragma unroll
      for (int ks = 0; ks < 2; ks++) {
        int row = f * 16 + lr;
        int cb = ks * 64 + lg * 16;
        bf16x8 kf = *(const bf16x8*)(K + row * 128 + (cb ^ ((row & 7) << 4)));
        s = __builtin_amdgcn_mfma_f32_16x16x32_bf16(kf, qf[ks], s, 0, 0, 0);
      }
#pragma unroll
      for (int i = 0; i < 4; i++) sv[f][i] = s[i];
    }
    __builtin_amdgcn_s_setprio(0);
    if (diag) {
      int qr = moff + wid * 16 + lr;
#pragma unroll
      for (int f = 0; f < 8; f++)
#pragma unroll
        for (int i = 0; i < 4; i++)
          if (f * 16 + lg * 4 + i > qr) sv[f][i] = NINF;
    }
    // fixed-max softmax: p = 2^(s*CEXP + NMC); fully lane-local
    float ps[8][4];
    float fs[8];
#pragma unroll
    for (int f = 0; f < 8; f++) {
#pragma unroll
      for (int i = 0; i < 4; i++)
        ps[f][i] = exp2f(__builtin_fmaf(sv[f][i], CEXP, NMC));
      fs[f] = (ps[f][0] + ps[f][1]) + (ps[f][2] + ps[f][3]);
    }
    l_part += ((fs[0] + fs[1]) + (fs[2] + fs[3])) +
              ((fs[4] + fs[5]) + (fs[6] + fs[7]));
    // P[q=lr][kv]: pack 4 consecutive kv via 2 cvt_pk -> one 8B swizzled write
#pragma unroll
    for (int f = 0; f < 8; f++) {
      union { unsigned u[2]; uint2 v; } pk;
      pk.u[0] = cvtpk(ps[f][0], ps[f][1]);
      pk.u[1] = cvtpk(ps[f][2], ps[f][3]);
      int cby = (f * 32 + lg * 8) ^ ((lr & 7) << 4);
      *(uint2*)((char*)pb + lr * 256 + cby) = pk.v;
    }
    asm volatile("s_waitcnt lgkmcnt(0)" ::: "memory");
    __builtin_amdgcn_s_setprio(1);
#pragma unroll
    for (int ks = 0; ks < 4; ks++) {
      int cb = ks * 64 + lg * 16;
      bf16x8 pf = *(const bf16x8*)((const char*)pb + lr * 256 + (cb ^ ((lr & 7) << 4)));
#pragma unroll
      for (int df = 0; df < 4; df++) {
        int vrow = df * 16 + lr;
        bf16x8 vf = *(const bf16x8*)(V + vrow * 256 + (cb ^ ((vrow & 7) << 4)));
        o[df] = __builtin_amdgcn_mfma_f32_16x16x32_bf16(vf, pf, o[df], 0, 0, 0);
      }
    }
    __builtin_amdgcn_s_setprio(0);
  };

  for (int kt = 0; kt <= hi_last; kt++) {
    stage(kt);
    __syncthreads();
    compute(kt == hi_last, (t_hi & 3) << 5, qhi, ohi, lhi);
    if (kt <= lo_last) compute(kt == lo_last, (t_lo & 3) << 5, qlo, olo, llo);
    __syncthreads();
  }

  const int bb = bh >> 4, h = bh & 15;
  auto epi = [&](int qt, const f32x4* o, float l_part) {
    float l = l_part;
    l += __shfl_xor(l, 16);
    l += __shfl_xor(l, 32);
    float rinv = 1.0f / l;
    int t = qt * 32 + wid * 16 + lr;
    size_t rowb = ((size_t)bb * 2048 + t) * 1024 + h * 64;
#pragma unroll
    for (int df = 0; df < 4; df++) {
      union { unsigned u[2]; uint2 v; } pk;
      pk.u[0] = cvtpk(o[df][0] * rinv, o[df][1] * rinv);
      pk.u[1] = cvtpk(o[df][2] * rinv, o[df][3] * rinv);
      *(uint2*)(attn + rowb + df * 16 + lg * 4) = pk.v;
    }
  };
  epi(t_lo, olo, llo);
  epi(t_hi, ohi, lhi);
}

// ---------------- GEMM2: out = attn @ WoutT^T + b_out (fp32 out) ----------------
// 64x128 tiles -> dim3(64,8) = 512 blocks = 2 blocks/CU; LDS 12 KB.
__global__ __launch_bounds__(256) void k_gemm_out(const u16t* __restrict__ attn,
                                                  const u16t* __restrict__ wt,
                                                  const float* __restrict__ bias,
                                                  float* __restrict__ out) {
  __shared__ u16t ldsA[64 * 32];
  __shared__ u16t ldsB[128 * 32];
  const int m0 = blockIdx.x * 64, n0 = blockIdx.y * 128;
  f32x4 acc[2][4];
  gemm_mainloop_t<1024, 64, 128>(attn, wt, m0, n0, ldsA, ldsB, acc);

  const int lane = threadIdx.x & 63, wid = threadIdx.x >> 6;
  const int wm = wid >> 1, wn = wid & 1;
#pragma unroll
  for (int fm = 0; fm < 2; fm++) {
    int row = m0 + wm * 32 + fm * 16 + (lane >> 4) * 4;
#pragma unroll
    for (int fn = 0; fn < 4; fn++) {
      int col = n0 + wn * 64 + fn * 16 + (lane & 15);
      float bv = bias[col];
#pragma unroll
      for (int i = 0; i < 4; i++)
        out[(size_t)(row + i) * 1024 + col] = acc[fm][fn][i] + bv;
    }
  }
}

extern "C" void kernel_launch(void* const* d_in, const int* in_sizes, int n_in,
                              void* d_out, int out_size, void* d_ws, size_t ws_size,
                              hipStream_t stream) {
  const float* x     = (const float*)d_in[0];
  const float* W_qkv = (const float*)d_in[1];
  const float* b_qkv = (const float*)d_in[2];
  const float* W_out = (const float*)d_in[3];
  const float* b_out = (const float*)d_in[4];
  float* out = (float*)d_out;

  char* ws = (char*)d_ws;
  u16t* xb    = (u16t*)(ws);
  u16t* wqkvT = (u16t*)(ws + 8388608);
  u16t* woutT = (u16t*)(ws + 14680064);
  u16t* qb    = (u16t*)(ws + 16777216);
  u16t* kb    = (u16t*)(ws + 25165824);
  u16t* vtb   = (u16t*)(ws + 33554432);
  u16t* attnb = (u16t*)(ws + 41943040);

  k_prep<<<3072, 256, 0, stream>>>(x, xb, W_qkv, wqkvT, W_out, woutT);
  k_gemm_qkv<<<dim3(32, 24), 256, 0, stream>>>(xb, wqkvT, b_qkv, qb, kb, vtb);
  k_attn<<<1024, 128, 0, stream>>>(qb, kb, vtb, attnb);
  k_gemm_out<<<dim3(64, 8), 256, 0, stream>>>(attnb, woutT, b_out, out);
}